// Round 18
// baseline (196.891 us; speedup 1.0000x reference)
//
#include <hip/hip_runtime.h>

#define IMGW 120
#define IMGH 120
#define NPIX 14400      // 120*120
#define XS   460800     // per (b,h) slice stride in elements = 14400*32

typedef unsigned short u16;
typedef short bf16x8 __attribute__((ext_vector_type(8)));
typedef float f32x4 __attribute__((ext_vector_type(4)));

#if __has_builtin(__builtin_amdgcn_exp2f)
#define EXP2(x) __builtin_amdgcn_exp2f(x)
#else
#define EXP2(x) exp2f(x)
#endif

// HW packed f32->bf16 (RNE, bit-identical to the +0x7FFF bit trick for non-NaN)
__device__ inline unsigned int cvtpk(float a, float b) {
  unsigned int r;
  asm("v_cvt_pk_bf16_f32 %0, %1, %2" : "=v"(r) : "v"(a), "v"(b));
  return r;
}
__device__ inline u16 f2bf(float f) {
  unsigned int x = __float_as_uint(f);
  unsigned int r = x + 0x7FFFu + ((x >> 16) & 1u);
  return (u16)(r >> 16);
}
__device__ inline float bflo(unsigned int u) { return __uint_as_float(u << 16); }
__device__ inline float bfhi(unsigned int u) { return __uint_as_float(u & 0xFFFF0000u); }

// ---------------- P1: weight convert f32 -> bf16 (Wq pre-scaled by 32^-0.5) ----------------
__global__ __launch_bounds__(256) void wconv_kernel(
    const float* __restrict__ Wq, const float* __restrict__ Wk,
    const float* __restrict__ Wv, const float* __restrict__ Wo,
    u16* __restrict__ Wb)
{
  const int t = threadIdx.x, bx = blockIdx.x, mat = blockIdx.y;
  const float* src = mat == 0 ? Wq : mat == 1 ? Wk : mat == 2 ? Wv : Wo;
  const float sc = (mat == 0) ? 0.17677669529663687f : 1.0f;
  const int e0 = (bx * 256 + t) * 4;
  float4 v = *(const float4*)(src + e0);
  uint2 u;
  u.x = cvtpk(v.x * sc, v.y * sc);
  u.y = cvtpk(v.z * sc, v.w * sc);
  *(uint2*)(Wb + (size_t)mat * 65536 + e0) = u;
}

// ---------------- K1: fused transpose + triple projection via MFMA ----------------
__global__ __launch_bounds__(256) void projmm_kernel(
    const float* __restrict__ x, const u16* __restrict__ Wb,
    u16* __restrict__ Qb, u16* __restrict__ Kb, u16* __restrict__ Vb)
{
  __shared__ u16 Xf[64 * 264];   // [pix][264], data cols 0..255 (row 528 B, 16B-aligned)
  const int t = threadIdx.x;
  const int lane = t & 63, wv = t >> 6;
  const int cc = lane & 15, kgrp = lane >> 4;
  const int p0 = blockIdx.x * 64;
  const int b  = blockIdx.y;
  const float* xb = x + (size_t)b * 256 * NPIX + p0;

  // --- stage: transpose-convert x tile (64 pix x 256 ch) -> Xf ---
  {
    unsigned int* X32 = (unsigned int*)Xf;
    const int pix4 = t & 15;
    #pragma unroll
    for (int it = 0; it < 8; ++it) {
      int j = (t >> 4) + it * 16;            // chpair 0..127
      float4 va = *(const float4*)(xb + (size_t)(2 * j) * NPIX + pix4 * 4);
      float4 vb = *(const float4*)(xb + (size_t)(2 * j + 1) * NPIX + pix4 * 4);
      X32[(pix4 * 4 + 0) * 132 + j] = cvtpk(va.x, vb.x);
      X32[(pix4 * 4 + 1) * 132 + j] = cvtpk(va.y, vb.y);
      X32[(pix4 * 4 + 2) * 132 + j] = cvtpk(va.z, vb.z);
      X32[(pix4 * 4 + 3) * 132 + j] = cvtpk(va.w, vb.w);
    }
  }
  __syncthreads();

  // --- per mat: barrier-free MFMA loop, A from global Wb, B from LDS ---
  for (int mat = 0; mat < 3; ++mat) {
    const u16* Wm = Wb + (size_t)mat * 65536;
    f32x4 acc[4][4];
    #pragma unroll
    for (int i = 0; i < 4; ++i)
      #pragma unroll
      for (int j = 0; j < 4; ++j) acc[i][j] = {0.f, 0.f, 0.f, 0.f};

    for (int kk = 0; kk < 8; ++kk) {
      bf16x8 af[4], bfr[4];
      #pragma unroll
      for (int f = 0; f < 4; ++f)
        af[f] = *(const bf16x8*)(Wm + (size_t)(wv * 64 + f * 16 + cc) * 256 + kk * 32 + kgrp * 8);
      #pragma unroll
      for (int nt = 0; nt < 4; ++nt)
        bfr[nt] = *(const bf16x8*)&Xf[(nt * 16 + cc) * 264 + kk * 32 + kgrp * 8];
      #pragma unroll
      for (int df = 0; df < 4; ++df)
        #pragma unroll
        for (int pf = 0; pf < 4; ++pf)
          acc[df][pf] = __builtin_amdgcn_mfma_f32_16x16x32_bf16(af[df], bfr[pf], acc[df][pf], 0, 0, 0);
    }

    u16* O = (mat == 0) ? Qb : (mat == 1) ? Kb : Vb;
    #pragma unroll
    for (int df = 0; df < 4; ++df) {
      int dim0 = wv * 64 + df * 16 + kgrp * 4;
      int h = dim0 >> 5, dl0 = dim0 & 31;
      #pragma unroll
      for (int pf = 0; pf < 4; ++pf) {
        int pix = p0 + pf * 16 + cc;
        f32x4 v = acc[df][pf];
        uint2 u;
        u.x = cvtpk(v[0], v[1]);
        u.y = cvtpk(v[2], v[3]);
        *(uint2*)&O[((size_t)(b * 8 + h) * NPIX + pix) * 32 + dl0] = u;
      }
    }
  }
}

// ---------------- K2: fused window attention, 4 independent (window,head) waves / block ----------------
// Per-wave barrier-free design; raw v_exp_f32, all-DPP reduce, paired-pp packed A-stores,
// HW cvt_pk bf16 conversions. Each wave owns an 11536 B LDS slice; block = 46144 B -> 3 blocks/CU.
__global__ __launch_bounds__(256) void attn_kernel(
    const u16* __restrict__ Qb,   // bf16 [b8h][pix][32]
    const u16* __restrict__ Kb,
    const u16* __restrict__ Vb,
    u16* __restrict__ AO)         // bf16 [b8h][pix][32]
{
  __shared__ __align__(16) unsigned char smem_all[4 * 11536];
  unsigned char* smem = smem_all + (threadIdx.x >> 6) * 11536;
  float* SA   = (float*)smem;               // 25 rows x 272 B (stride 68 f32)
  u16*   vsT  = (u16*)(smem + 6800);        // [32][72] V transposed [d][pp]
  float* drow = (float*)(smem + 11408);     // [32] rinv per q

  const int lane = threadIdx.x & 63;
  const int wh = blockIdx.x * 4 + (threadIdx.x >> 6);
  const int h = wh / 2304;
  const int w = wh % 2304;
  const int b = w / 576;
  const int rr = w % 576;
  const int by = rr / 24, bx = rr % 24;
  const int y0 = by * 5, x0 = bx * 5;
  const size_t gbase = (size_t)(b * 8 + h) * XS;
  const u16* Qg = Qb + gbase;
  const u16* Kg = Kb + gbase;
  const u16* Vg = Vb + gbase;

  const int cc = lane & 15, kgrp = lane >> 4;
  const int ks8 = kgrp * 8;
  const int r0 = kgrp * 4;
  const int kpl = lane & 31;

  // determinism hygiene: drow tail (read as float4, results discarded) gets zeros
  if (lane >= 25 && lane < 32) drow[lane] = 0.f;

  // --- Q A-frags direct from global (rows q>=25 garbage-inert) ---
  bf16x8 aq0, aq1;
  {
    int rA = cc;                 // < 25 always
    int wyA = (rA * 13) >> 6, wxA = rA - wyA * 5;
    uint4 uA = *(const uint4*)(Qg + (size_t)((y0 + wyA) * IMGW + x0 + wxA) * 32 + ks8);
    aq0 = *(bf16x8*)&uA;
    int rB = cc + 16; int rBc = rB < 25 ? rB : 0;
    int wyB = (rBc * 13) >> 6, wxB = rBc - wyB * 5;
    uint4 uB = *(const uint4*)(Qg + (size_t)((y0 + wyB) * IMGW + x0 + wxB) * 32 + ks8);
    aq1 = *(bf16x8*)&uB;
  }

  // --- K B-frags direct from global (pp<49 OOB -> exact zero; pp>=49 inert) ---
  bf16x8 bk[4];
  #pragma unroll
  for (int nt = 0; nt < 4; ++nt) {
    int pp = cc + nt * 16;
    int hy = (pp * 37) >> 8, hx = pp - hy * 7;
    int gy = y0 - 1 + hy, gx = x0 - 1 + hx;
    bool inb = (gy >= 0) && (gy < IMGH) && (gx >= 0) && (gx < IMGW);
    int gyc = min(max(gy, 0), IMGH - 1), gxc = min(max(gx, 0), IMGW - 1);
    uint4 u = *(const uint4*)(Kg + (size_t)(gyc * IMGW + gxc) * 32 + ks8);
    if (pp < 49 && !inb) u = make_uint4(0u, 0u, 0u, 0u);
    bk[nt] = *(bf16x8*)&u;
  }

  // --- V halo -> vsT[d][pp] (zero-filled) ---
  #pragma unroll
  for (int it = 0; it < 4; ++it) {
    int f = lane + 64 * it;
    int pp = f >> 2, c = f & 3;
    int hy = (pp * 37) >> 8, hx = pp - hy * 7;
    int gy = y0 - 1 + hy, gx = x0 - 1 + hx;
    uint4 u = make_uint4(0u, 0u, 0u, 0u);
    if (pp < 49 && gy >= 0 && gy < IMGH && gx >= 0 && gx < IMGW)
      u = *(const uint4*)(Vg + (size_t)(gy * IMGW + gx) * 32 + c * 8);
    const int d0 = c * 8;
    vsT[(d0 + 0) * 72 + pp] = (u16)(u.x & 0xffff);
    vsT[(d0 + 1) * 72 + pp] = (u16)(u.x >> 16);
    vsT[(d0 + 2) * 72 + pp] = (u16)(u.y & 0xffff);
    vsT[(d0 + 3) * 72 + pp] = (u16)(u.y >> 16);
    vsT[(d0 + 4) * 72 + pp] = (u16)(u.z & 0xffff);
    vsT[(d0 + 5) * 72 + pp] = (u16)(u.z >> 16);
    vsT[(d0 + 6) * 72 + pp] = (u16)(u.w & 0xffff);
    vsT[(d0 + 7) * 72 + pp] = (u16)(u.w >> 16);
  }

  // --- QK^T via MFMA, scatter to SA (same-wave DS ordering, no barrier) ---
  {
    const f32x4 z = {0.f, 0.f, 0.f, 0.f};
    f32x4 s[2][4];
    #pragma unroll
    for (int nt = 0; nt < 4; ++nt) {
      s[0][nt] = __builtin_amdgcn_mfma_f32_16x16x32_bf16(aq0, bk[nt], z, 0, 0, 0);
      s[1][nt] = __builtin_amdgcn_mfma_f32_16x16x32_bf16(aq1, bk[nt], z, 0, 0, 0);
    }
    #pragma unroll
    for (int mt = 0; mt < 2; ++mt)
      #pragma unroll
      for (int nt = 0; nt < 4; ++nt)
        #pragma unroll
        for (int i = 0; i < 4; ++i) {
          int q = mt * 16 + r0 + i, pp = nt * 16 + cc;
          if (q < 25 && pp < 49) SA[q * 68 + pp] = s[mt][nt][i];
        }
  }

  // --- fold constants (loop-invariant): paired-pp mapping ppA=2*kpl, ppB=2*kpl+1 ---
  int idxA[9], idxB[9];
  float selA[9], selB[9];
  {
    const int hb = lane & 32;
    const int ppA = 2 * kpl, ppB = 2 * kpl + 1;
    const int hyA = (ppA * 37) >> 8, hxA = ppA - hyA * 7;
    const int hyB = (ppB * 37) >> 8, hxB = ppB - hyB * 7;
    #pragma unroll
    for (int dy = 0; dy < 3; ++dy)
      #pragma unroll
      for (int dx = 0; dx < 3; ++dx) {
        int j = dy * 3 + dx;
        int kyA = hyA - dy, kxA = hxA - dx;
        bool vA = (ppA < 49) && ((unsigned)kyA < 5u) && ((unsigned)kxA < 5u);
        idxA[j] = (hb + (vA ? kyA * 5 + kxA : 0)) << 2;
        selA[j] = vA ? 1.f : 0.f;
        int kyB = hyB - dy, kxB = hxB - dx;
        bool vB = (ppB < 49) && ((unsigned)kyB < 5u) && ((unsigned)kxB < 5u);
        idxB[j] = (hb + (vB ? kyB * 5 + kxB : 0)) << 2;
        selB[j] = vB ? 1.f : 0.f;
      }
  }

  // --- expand -> exp2-shifted softmax -> bpermute fold (barrier-free) ---
  const float DPN = 11.f / 6.f;
  const float LOG2E = 1.44269504f;
  const int kyq = (kpl * 13) >> 6, kxq = kpl - kyq * 5;
  const int sboff = kyq * 7 + kxq;

  for (int t = 0; t < 13; ++t) {
    const int q = 2 * t + (lane >> 5);
    const bool act = (kpl < 25) && (q < 25);
    const float* sp = SA + q * 68 + sboff;
    float s0 = sp[0], s1 = sp[1], s2 = sp[2];
    float s3 = sp[7], s4 = sp[8], s5 = sp[9];
    float s6 = sp[14], s7 = sp[15], s8 = sp[16];

    float st = ((s0 + s1) + (s2 + s3)) + ((s5 + s6) + (s7 + s8)) + s4;
    float l0 = -0.375f * st + 4.375f * s4;
    float base = -0.5f * st + DPN * s4;
    float l1 = base + DPN * (s1 + s7);
    float l2 = base + DPN * (s3 + s5);
    float l3 = base + DPN * (s0 + s8);
    float l4 = base + DPN * (s2 + s6);
    float l5 = base + DPN * (s1 + s3);
    float l6 = base + DPN * (s1 + s5);
    float l7 = base + DPN * (s3 + s7);
    float l8 = base + DPN * (s5 + s7);

    float p0 = EXP2(fmaf(l0, LOG2E, -32.f));
    float p1 = EXP2(fmaf(l1, LOG2E, -32.f));
    float p2 = EXP2(fmaf(l2, LOG2E, -32.f));
    float p3 = EXP2(fmaf(l3, LOG2E, -32.f));
    float p4 = EXP2(fmaf(l4, LOG2E, -32.f));
    float p5 = EXP2(fmaf(l5, LOG2E, -32.f));
    float p6 = EXP2(fmaf(l6, LOG2E, -32.f));
    float p7 = EXP2(fmaf(l7, LOG2E, -32.f));
    float p8 = EXP2(fmaf(l8, LOG2E, -32.f));
    float ps = ((p0 + p1) + (p2 + p3)) + ((p4 + p5) + (p6 + p7)) + p8;

    // denominator reduce, all-DPP (no DS ops); half-total lands at lanes 31/63
    float sv = act ? ps : 0.f;
    sv += __int_as_float(__builtin_amdgcn_update_dpp(0, __float_as_int(sv), 0xB1, 0xF, 0xF, true));
    sv += __int_as_float(__builtin_amdgcn_update_dpp(0, __float_as_int(sv), 0x4E, 0xF, 0xF, true));
    sv += __int_as_float(__builtin_amdgcn_update_dpp(0, __float_as_int(sv), 0x124, 0xF, 0xF, true));
    sv += __int_as_float(__builtin_amdgcn_update_dpp(0, __float_as_int(sv), 0x128, 0xF, 0xF, true));
    sv += __int_as_float(__builtin_amdgcn_update_dpp(0, __float_as_int(sv), 0x142, 0xF, 0xF, true));
    if (kpl == 31 && q < 25) drow[q] = __builtin_amdgcn_rcpf(sv + 1e-35f);

    // per-offset fold coefficients (unscaled; rinv deferred to PV epilogue)
    float psm0 = ps - p0;
    float basec = -0.5f * psm0 - 0.375f * p0;
    float cv[9];
    cv[0] = basec + DPN * p3;
    cv[1] = basec + DPN * ((p1 + p5) + p6);
    cv[2] = basec + DPN * p4;
    cv[3] = basec + DPN * ((p2 + p5) + p7);
    cv[4] = 4.f * p0 + (4.f / 3.f) * psm0;
    cv[5] = basec + DPN * ((p2 + p6) + p8);
    cv[6] = basec + DPN * p4;
    cv[7] = basec + DPN * ((p1 + p7) + p8);
    cv[8] = basec + DPN * p3;

    // fold via bpermute: pass A -> pp = 2*kpl, pass B -> pp = 2*kpl+1
    float a = 0.f, a2 = 0.f;
    #pragma unroll
    for (int j = 0; j < 9; ++j) {
      int cj = __float_as_int(cv[j]);
      a  = fmaf(selA[j], __int_as_float(__builtin_amdgcn_ds_bpermute(idxA[j], cj)), a);
      a2 = fmaf(selB[j], __int_as_float(__builtin_amdgcn_ds_bpermute(idxB[j], cj)), a2);
    }

    if (q < 25) {
      // packed A-stores via HW cvt_pk: adjacent pp pair -> one b32 hi, one b32 lo
      unsigned int* arow32 = (unsigned int*)((char*)SA + q * 272);
      unsigned int hi2 = cvtpk(a, a2);
      arow32[kpl] = hi2;
      float rA = a  - bflo(hi2);
      float rB = a2 - bfhi(hi2);
      arow32[32 + kpl] = cvtpk(rA, rB);
    }
  }

  __syncthreads();   // all 4 waves reach unconditionally; per-wave data private

  // --- PV via MFMA (hi/lo compensated A), rinv epilogue ---
  {
    f32x4 o[2][2];
    #pragma unroll
    for (int i = 0; i < 2; ++i)
      #pragma unroll
      for (int j = 0; j < 2; ++j) o[i][j] = {0.f, 0.f, 0.f, 0.f};
    #pragma unroll
    for (int kx = 0; kx < 2; ++kx) {
      const int koff = kx * 64 + kgrp * 16;         // byte offset within hi block
      const char* sa = (const char*)SA;
      bf16x8 ah0 = *(const bf16x8*)(sa + cc * 272 + koff);
      bf16x8 ah1 = *(const bf16x8*)(sa + (cc + 16) * 272 + koff);
      bf16x8 al0 = *(const bf16x8*)(sa + cc * 272 + 128 + koff);
      bf16x8 al1 = *(const bf16x8*)(sa + (cc + 16) * 272 + 128 + koff);
      bf16x8 b0  = *(const bf16x8*)&vsT[cc * 72 + kx * 32 + ks8];
      bf16x8 b1  = *(const bf16x8*)&vsT[(cc + 16) * 72 + kx * 32 + ks8];
      o[0][0] = __builtin_amdgcn_mfma_f32_16x16x32_bf16(ah0, b0, o[0][0], 0, 0, 0);
      o[0][0] = __builtin_amdgcn_mfma_f32_16x16x32_bf16(al0, b0, o[0][0], 0, 0, 0);
      o[0][1] = __builtin_amdgcn_mfma_f32_16x16x32_bf16(ah0, b1, o[0][1], 0, 0, 0);
      o[0][1] = __builtin_amdgcn_mfma_f32_16x16x32_bf16(al0, b1, o[0][1], 0, 0, 0);
      o[1][0] = __builtin_amdgcn_mfma_f32_16x16x32_bf16(ah1, b0, o[1][0], 0, 0, 0);
      o[1][0] = __builtin_amdgcn_mfma_f32_16x16x32_bf16(al1, b0, o[1][0], 0, 0, 0);
      o[1][1] = __builtin_amdgcn_mfma_f32_16x16x32_bf16(ah1, b1, o[1][1], 0, 0, 0);
      o[1][1] = __builtin_amdgcn_mfma_f32_16x16x32_bf16(al1, b1, o[1][1], 0, 0, 0);
    }
    #pragma unroll
    for (int mt = 0; mt < 2; ++mt) {
      float4 rv = *(const float4*)&drow[mt * 16 + r0];
      #pragma unroll
      for (int i = 0; i < 4; ++i) {
        int q = mt * 16 + r0 + i;
        if (q < 25) {
          int qy = (q * 13) >> 6, qx = q - qy * 5;
          u16* dst = AO + gbase + ((size_t)((y0 + qy) * IMGW + x0 + qx)) * 32;
          float r = (&rv.x)[i];
          unsigned int pk = cvtpk(o[mt][0][i] * r, o[mt][1][i] * r);
          dst[cc]      = (u16)(pk & 0xffff);
          dst[cc + 16] = (u16)(pk >> 16);
        }
      }
    }
  }
}

// ---------------- K3: output projection via MFMA — LDS-free, barrier-free ----------------
__global__ __launch_bounds__(256) void outmm_kernel(
    const u16* __restrict__ AOb, const u16* __restrict__ Wb,
    const float* __restrict__ bout, float* __restrict__ O)
{
  const int t = threadIdx.x;
  const int lane = t & 63, wv = t >> 6;
  const int cc = lane & 15, kgrp = lane >> 4;
  const int p0 = blockIdx.x * 64;
  const int b  = blockIdx.y;
  const u16* Wm = Wb + (size_t)3 * 65536;

  f32x4 acc[4][4];
  #pragma unroll
  for (int i = 0; i < 4; ++i)
    #pragma unroll
    for (int j = 0; j < 4; ++j) acc[i][j] = {0.f, 0.f, 0.f, 0.f};

  for (int kk = 0; kk < 8; ++kk) {
    bf16x8 af[4], bfr[4];
    #pragma unroll
    for (int f = 0; f < 4; ++f)
      af[f] = *(const bf16x8*)(Wm + (size_t)(wv * 64 + f * 16 + cc) * 256 + kk * 32 + kgrp * 8);
    #pragma unroll
    for (int nt = 0; nt < 4; ++nt)
      bfr[nt] = *(const bf16x8*)(AOb + ((size_t)(b * 8 + kk) * NPIX + p0 + nt * 16 + cc) * 32 + kgrp * 8);
    #pragma unroll
    for (int df = 0; df < 4; ++df)
      #pragma unroll
      for (int pf = 0; pf < 4; ++pf)
        acc[df][pf] = __builtin_amdgcn_mfma_f32_16x16x32_bf16(af[df], bfr[pf], acc[df][pf], 0, 0, 0);
  }

  #pragma unroll
  for (int df = 0; df < 4; ++df) {
    int dim0 = wv * 64 + df * 16 + kgrp * 4;
    float4 bv = *(const float4*)&bout[dim0];
    #pragma unroll
    for (int pf = 0; pf < 4; ++pf) {
      int pix = p0 + pf * 16 + cc;
      f32x4 v = acc[df][pf];
      float* ob = O + (size_t)b * 256 * NPIX + pix;
      ob[(size_t)(dim0 + 0) * NPIX] = v[0] + bv.x;
      ob[(size_t)(dim0 + 1) * NPIX] = v[1] + bv.y;
      ob[(size_t)(dim0 + 2) * NPIX] = v[2] + bv.z;
      ob[(size_t)(dim0 + 3) * NPIX] = v[3] + bv.w;
    }
  }
}

extern "C" void kernel_launch(void* const* d_in, const int* in_sizes, int n_in,
                              void* d_out, int out_size, void* d_ws, size_t ws_size,
                              hipStream_t stream) {
  const float* x    = (const float*)d_in[0];
  const float* Wk   = (const float*)d_in[2];
  const float* Wv   = (const float*)d_in[3];
  const float* Wq   = (const float*)d_in[4];
  const float* Wout = (const float*)d_in[5];
  const float* bout = (const float*)d_in[6];

  // d_out: Qb bf16 (29,491,200 B) at base; overwritten by outmm's f32 output later
  u16* Qb  = (u16*)d_out;
  // ws: Kb | Vb | AOb (bf16) | Wb
  u16* Kb  = (u16*)d_ws;
  u16* Vb  = Kb + (size_t)4 * NPIX * 256;
  u16* AOb = Vb + (size_t)4 * NPIX * 256;
  u16* Wb  = AOb + (size_t)4 * NPIX * 256;

  wconv_kernel<<<dim3(64, 4), 256, 0, stream>>>(Wq, Wk, Wv, Wout, Wb);
  projmm_kernel<<<dim3(225, 4), 256, 0, stream>>>(x, Wb, Qb, Kb, Vb);
  attn_kernel<<<dim3(4608), 256, 0, stream>>>(Qb, Kb, Vb, AOb);
  outmm_kernel<<<dim3(225, 4), 256, 0, stream>>>(AOb, Wb, bout, (float*)d_out);
}

// Round 19
// 191.898 us; speedup vs baseline: 1.0260x; 1.0260x over previous
//
#include <hip/hip_runtime.h>

#define IMGW 120
#define IMGH 120
#define NPIX 14400      // 120*120
#define XS   460800     // per (b,h) slice stride in elements = 14400*32

typedef unsigned short u16;
typedef short bf16x8 __attribute__((ext_vector_type(8)));
typedef float f32x4 __attribute__((ext_vector_type(4)));

#if __has_builtin(__builtin_amdgcn_exp2f)
#define EXP2(x) __builtin_amdgcn_exp2f(x)
#else
#define EXP2(x) exp2f(x)
#endif

// HW packed f32->bf16 (RNE) — used ONLY in attn, where DS latency hides the asm fence.
__device__ inline unsigned int cvtpk(float a, float b) {
  unsigned int r;
  asm("v_cvt_pk_bf16_f32 %0, %1, %2" : "=v"(r) : "v"(a), "v"(b));
  return r;
}
// Schedulable pure-ALU f32->bf16 (bit-identical to RNE) — used in GEMM staging paths.
__device__ inline u16 f2bf(float f) {
  unsigned int x = __float_as_uint(f);
  unsigned int r = x + 0x7FFFu + ((x >> 16) & 1u);
  return (u16)(r >> 16);
}
__device__ inline unsigned int pk2(float a, float b) {
  return (unsigned int)f2bf(a) | ((unsigned int)f2bf(b) << 16);
}
__device__ inline float bflo(unsigned int u) { return __uint_as_float(u << 16); }
__device__ inline float bfhi(unsigned int u) { return __uint_as_float(u & 0xFFFF0000u); }

// ---------------- P1: weight convert f32 -> bf16 (Wq pre-scaled by 32^-0.5) ----------------
__global__ __launch_bounds__(256) void wconv_kernel(
    const float* __restrict__ Wq, const float* __restrict__ Wk,
    const float* __restrict__ Wv, const float* __restrict__ Wo,
    u16* __restrict__ Wb)
{
  const int t = threadIdx.x, bx = blockIdx.x, mat = blockIdx.y;
  const float* src = mat == 0 ? Wq : mat == 1 ? Wk : mat == 2 ? Wv : Wo;
  const float sc = (mat == 0) ? 0.17677669529663687f : 1.0f;
  const int e0 = (bx * 256 + t) * 4;
  float4 v = *(const float4*)(src + e0);
  uint2 u;
  u.x = pk2(v.x * sc, v.y * sc);
  u.y = pk2(v.z * sc, v.w * sc);
  *(uint2*)(Wb + (size_t)mat * 65536 + e0) = u;
}

// ---------------- K1: fused transpose + triple projection via MFMA ----------------
__global__ __launch_bounds__(256) void projmm_kernel(
    const float* __restrict__ x, const u16* __restrict__ Wb,
    u16* __restrict__ Qb, u16* __restrict__ Kb, u16* __restrict__ Vb)
{
  __shared__ u16 Xf[64 * 264];   // [pix][264], data cols 0..255 (row 528 B, 16B-aligned)
  const int t = threadIdx.x;
  const int lane = t & 63, wv = t >> 6;
  const int cc = lane & 15, kgrp = lane >> 4;
  const int p0 = blockIdx.x * 64;
  const int b  = blockIdx.y;
  const float* xb = x + (size_t)b * 256 * NPIX + p0;

  // --- stage: transpose-convert x tile (64 pix x 256 ch) -> Xf ---
  {
    unsigned int* X32 = (unsigned int*)Xf;
    const int pix4 = t & 15;
    #pragma unroll
    for (int it = 0; it < 8; ++it) {
      int j = (t >> 4) + it * 16;            // chpair 0..127
      float4 va = *(const float4*)(xb + (size_t)(2 * j) * NPIX + pix4 * 4);
      float4 vb = *(const float4*)(xb + (size_t)(2 * j + 1) * NPIX + pix4 * 4);
      X32[(pix4 * 4 + 0) * 132 + j] = pk2(va.x, vb.x);
      X32[(pix4 * 4 + 1) * 132 + j] = pk2(va.y, vb.y);
      X32[(pix4 * 4 + 2) * 132 + j] = pk2(va.z, vb.z);
      X32[(pix4 * 4 + 3) * 132 + j] = pk2(va.w, vb.w);
    }
  }
  __syncthreads();

  // --- per mat: barrier-free MFMA loop, A from global Wb, B from LDS ---
  for (int mat = 0; mat < 3; ++mat) {
    const u16* Wm = Wb + (size_t)mat * 65536;
    f32x4 acc[4][4];
    #pragma unroll
    for (int i = 0; i < 4; ++i)
      #pragma unroll
      for (int j = 0; j < 4; ++j) acc[i][j] = {0.f, 0.f, 0.f, 0.f};

    for (int kk = 0; kk < 8; ++kk) {
      bf16x8 af[4], bfr[4];
      #pragma unroll
      for (int f = 0; f < 4; ++f)
        af[f] = *(const bf16x8*)(Wm + (size_t)(wv * 64 + f * 16 + cc) * 256 + kk * 32 + kgrp * 8);
      #pragma unroll
      for (int nt = 0; nt < 4; ++nt)
        bfr[nt] = *(const bf16x8*)&Xf[(nt * 16 + cc) * 264 + kk * 32 + kgrp * 8];
      #pragma unroll
      for (int df = 0; df < 4; ++df)
        #pragma unroll
        for (int pf = 0; pf < 4; ++pf)
          acc[df][pf] = __builtin_amdgcn_mfma_f32_16x16x32_bf16(af[df], bfr[pf], acc[df][pf], 0, 0, 0);
    }

    u16* O = (mat == 0) ? Qb : (mat == 1) ? Kb : Vb;
    #pragma unroll
    for (int df = 0; df < 4; ++df) {
      int dim0 = wv * 64 + df * 16 + kgrp * 4;
      int h = dim0 >> 5, dl0 = dim0 & 31;
      #pragma unroll
      for (int pf = 0; pf < 4; ++pf) {
        int pix = p0 + pf * 16 + cc;
        f32x4 v = acc[df][pf];
        uint2 u;
        u.x = pk2(v[0], v[1]);
        u.y = pk2(v[2], v[3]);
        *(uint2*)&O[((size_t)(b * 8 + h) * NPIX + pix) * 32 + dl0] = u;
      }
    }
  }
}

// ---------------- K2: fused window attention, 4 independent (window,head) waves / block ----------------
// Per-wave barrier-free design; raw v_exp_f32, all-DPP reduce, paired-pp packed A-stores,
// HW cvt_pk bf16 conversions (fence harmless between DS ops). 4 x 11536 B LDS -> 3 blocks/CU.
__global__ __launch_bounds__(256) void attn_kernel(
    const u16* __restrict__ Qb,   // bf16 [b8h][pix][32]
    const u16* __restrict__ Kb,
    const u16* __restrict__ Vb,
    u16* __restrict__ AO)         // bf16 [b8h][pix][32]
{
  __shared__ __align__(16) unsigned char smem_all[4 * 11536];
  unsigned char* smem = smem_all + (threadIdx.x >> 6) * 11536;
  float* SA   = (float*)smem;               // 25 rows x 272 B (stride 68 f32)
  u16*   vsT  = (u16*)(smem + 6800);        // [32][72] V transposed [d][pp]
  float* drow = (float*)(smem + 11408);     // [32] rinv per q

  const int lane = threadIdx.x & 63;
  const int wh = blockIdx.x * 4 + (threadIdx.x >> 6);
  const int h = wh / 2304;
  const int w = wh % 2304;
  const int b = w / 576;
  const int rr = w % 576;
  const int by = rr / 24, bx = rr % 24;
  const int y0 = by * 5, x0 = bx * 5;
  const size_t gbase = (size_t)(b * 8 + h) * XS;
  const u16* Qg = Qb + gbase;
  const u16* Kg = Kb + gbase;
  const u16* Vg = Vb + gbase;

  const int cc = lane & 15, kgrp = lane >> 4;
  const int ks8 = kgrp * 8;
  const int r0 = kgrp * 4;
  const int kpl = lane & 31;

  // determinism hygiene: drow tail (read as float4, results discarded) gets zeros
  if (lane >= 25 && lane < 32) drow[lane] = 0.f;

  // --- Q A-frags direct from global (rows q>=25 garbage-inert) ---
  bf16x8 aq0, aq1;
  {
    int rA = cc;                 // < 25 always
    int wyA = (rA * 13) >> 6, wxA = rA - wyA * 5;
    uint4 uA = *(const uint4*)(Qg + (size_t)((y0 + wyA) * IMGW + x0 + wxA) * 32 + ks8);
    aq0 = *(bf16x8*)&uA;
    int rB = cc + 16; int rBc = rB < 25 ? rB : 0;
    int wyB = (rBc * 13) >> 6, wxB = rBc - wyB * 5;
    uint4 uB = *(const uint4*)(Qg + (size_t)((y0 + wyB) * IMGW + x0 + wxB) * 32 + ks8);
    aq1 = *(bf16x8*)&uB;
  }

  // --- K B-frags direct from global (pp<49 OOB -> exact zero; pp>=49 inert) ---
  bf16x8 bk[4];
  #pragma unroll
  for (int nt = 0; nt < 4; ++nt) {
    int pp = cc + nt * 16;
    int hy = (pp * 37) >> 8, hx = pp - hy * 7;
    int gy = y0 - 1 + hy, gx = x0 - 1 + hx;
    bool inb = (gy >= 0) && (gy < IMGH) && (gx >= 0) && (gx < IMGW);
    int gyc = min(max(gy, 0), IMGH - 1), gxc = min(max(gx, 0), IMGW - 1);
    uint4 u = *(const uint4*)(Kg + (size_t)(gyc * IMGW + gxc) * 32 + ks8);
    if (pp < 49 && !inb) u = make_uint4(0u, 0u, 0u, 0u);
    bk[nt] = *(bf16x8*)&u;
  }

  // --- V halo -> vsT[d][pp] (zero-filled) ---
  #pragma unroll
  for (int it = 0; it < 4; ++it) {
    int f = lane + 64 * it;
    int pp = f >> 2, c = f & 3;
    int hy = (pp * 37) >> 8, hx = pp - hy * 7;
    int gy = y0 - 1 + hy, gx = x0 - 1 + hx;
    uint4 u = make_uint4(0u, 0u, 0u, 0u);
    if (pp < 49 && gy >= 0 && gy < IMGH && gx >= 0 && gx < IMGW)
      u = *(const uint4*)(Vg + (size_t)(gy * IMGW + gx) * 32 + c * 8);
    const int d0 = c * 8;
    vsT[(d0 + 0) * 72 + pp] = (u16)(u.x & 0xffff);
    vsT[(d0 + 1) * 72 + pp] = (u16)(u.x >> 16);
    vsT[(d0 + 2) * 72 + pp] = (u16)(u.y & 0xffff);
    vsT[(d0 + 3) * 72 + pp] = (u16)(u.y >> 16);
    vsT[(d0 + 4) * 72 + pp] = (u16)(u.z & 0xffff);
    vsT[(d0 + 5) * 72 + pp] = (u16)(u.z >> 16);
    vsT[(d0 + 6) * 72 + pp] = (u16)(u.w & 0xffff);
    vsT[(d0 + 7) * 72 + pp] = (u16)(u.w >> 16);
  }

  // --- QK^T via MFMA, scatter to SA (same-wave DS ordering, no barrier) ---
  {
    const f32x4 z = {0.f, 0.f, 0.f, 0.f};
    f32x4 s[2][4];
    #pragma unroll
    for (int nt = 0; nt < 4; ++nt) {
      s[0][nt] = __builtin_amdgcn_mfma_f32_16x16x32_bf16(aq0, bk[nt], z, 0, 0, 0);
      s[1][nt] = __builtin_amdgcn_mfma_f32_16x16x32_bf16(aq1, bk[nt], z, 0, 0, 0);
    }
    #pragma unroll
    for (int mt = 0; mt < 2; ++mt)
      #pragma unroll
      for (int nt = 0; nt < 4; ++nt)
        #pragma unroll
        for (int i = 0; i < 4; ++i) {
          int q = mt * 16 + r0 + i, pp = nt * 16 + cc;
          if (q < 25 && pp < 49) SA[q * 68 + pp] = s[mt][nt][i];
        }
  }

  // --- fold constants (loop-invariant): paired-pp mapping ppA=2*kpl, ppB=2*kpl+1 ---
  int idxA[9], idxB[9];
  float selA[9], selB[9];
  {
    const int hb = lane & 32;
    const int ppA = 2 * kpl, ppB = 2 * kpl + 1;
    const int hyA = (ppA * 37) >> 8, hxA = ppA - hyA * 7;
    const int hyB = (ppB * 37) >> 8, hxB = ppB - hyB * 7;
    #pragma unroll
    for (int dy = 0; dy < 3; ++dy)
      #pragma unroll
      for (int dx = 0; dx < 3; ++dx) {
        int j = dy * 3 + dx;
        int kyA = hyA - dy, kxA = hxA - dx;
        bool vA = (ppA < 49) && ((unsigned)kyA < 5u) && ((unsigned)kxA < 5u);
        idxA[j] = (hb + (vA ? kyA * 5 + kxA : 0)) << 2;
        selA[j] = vA ? 1.f : 0.f;
        int kyB = hyB - dy, kxB = hxB - dx;
        bool vB = (ppB < 49) && ((unsigned)kyB < 5u) && ((unsigned)kxB < 5u);
        idxB[j] = (hb + (vB ? kyB * 5 + kxB : 0)) << 2;
        selB[j] = vB ? 1.f : 0.f;
      }
  }

  // --- expand -> exp2-shifted softmax -> bpermute fold (barrier-free) ---
  const float DPN = 11.f / 6.f;
  const float LOG2E = 1.44269504f;
  const int kyq = (kpl * 13) >> 6, kxq = kpl - kyq * 5;
  const int sboff = kyq * 7 + kxq;

  for (int t = 0; t < 13; ++t) {
    const int q = 2 * t + (lane >> 5);
    const bool act = (kpl < 25) && (q < 25);
    const float* sp = SA + q * 68 + sboff;
    float s0 = sp[0], s1 = sp[1], s2 = sp[2];
    float s3 = sp[7], s4 = sp[8], s5 = sp[9];
    float s6 = sp[14], s7 = sp[15], s8 = sp[16];

    float st = ((s0 + s1) + (s2 + s3)) + ((s5 + s6) + (s7 + s8)) + s4;
    float l0 = -0.375f * st + 4.375f * s4;
    float base = -0.5f * st + DPN * s4;
    float l1 = base + DPN * (s1 + s7);
    float l2 = base + DPN * (s3 + s5);
    float l3 = base + DPN * (s0 + s8);
    float l4 = base + DPN * (s2 + s6);
    float l5 = base + DPN * (s1 + s3);
    float l6 = base + DPN * (s1 + s5);
    float l7 = base + DPN * (s3 + s7);
    float l8 = base + DPN * (s5 + s7);

    float p0 = EXP2(fmaf(l0, LOG2E, -32.f));
    float p1 = EXP2(fmaf(l1, LOG2E, -32.f));
    float p2 = EXP2(fmaf(l2, LOG2E, -32.f));
    float p3 = EXP2(fmaf(l3, LOG2E, -32.f));
    float p4 = EXP2(fmaf(l4, LOG2E, -32.f));
    float p5 = EXP2(fmaf(l5, LOG2E, -32.f));
    float p6 = EXP2(fmaf(l6, LOG2E, -32.f));
    float p7 = EXP2(fmaf(l7, LOG2E, -32.f));
    float p8 = EXP2(fmaf(l8, LOG2E, -32.f));
    float ps = ((p0 + p1) + (p2 + p3)) + ((p4 + p5) + (p6 + p7)) + p8;

    // denominator reduce, all-DPP (no DS ops); half-total lands at lanes 31/63
    float sv = act ? ps : 0.f;
    sv += __int_as_float(__builtin_amdgcn_update_dpp(0, __float_as_int(sv), 0xB1, 0xF, 0xF, true));
    sv += __int_as_float(__builtin_amdgcn_update_dpp(0, __float_as_int(sv), 0x4E, 0xF, 0xF, true));
    sv += __int_as_float(__builtin_amdgcn_update_dpp(0, __float_as_int(sv), 0x124, 0xF, 0xF, true));
    sv += __int_as_float(__builtin_amdgcn_update_dpp(0, __float_as_int(sv), 0x128, 0xF, 0xF, true));
    sv += __int_as_float(__builtin_amdgcn_update_dpp(0, __float_as_int(sv), 0x142, 0xF, 0xF, true));
    if (kpl == 31 && q < 25) drow[q] = __builtin_amdgcn_rcpf(sv + 1e-35f);

    // per-offset fold coefficients (unscaled; rinv deferred to PV epilogue)
    float psm0 = ps - p0;
    float basec = -0.5f * psm0 - 0.375f * p0;
    float cv[9];
    cv[0] = basec + DPN * p3;
    cv[1] = basec + DPN * ((p1 + p5) + p6);
    cv[2] = basec + DPN * p4;
    cv[3] = basec + DPN * ((p2 + p5) + p7);
    cv[4] = 4.f * p0 + (4.f / 3.f) * psm0;
    cv[5] = basec + DPN * ((p2 + p6) + p8);
    cv[6] = basec + DPN * p4;
    cv[7] = basec + DPN * ((p1 + p7) + p8);
    cv[8] = basec + DPN * p3;

    // fold via bpermute: pass A -> pp = 2*kpl, pass B -> pp = 2*kpl+1
    float a = 0.f, a2 = 0.f;
    #pragma unroll
    for (int j = 0; j < 9; ++j) {
      int cj = __float_as_int(cv[j]);
      a  = fmaf(selA[j], __int_as_float(__builtin_amdgcn_ds_bpermute(idxA[j], cj)), a);
      a2 = fmaf(selB[j], __int_as_float(__builtin_amdgcn_ds_bpermute(idxB[j], cj)), a2);
    }

    if (q < 25) {
      // packed A-stores via HW cvt_pk: adjacent pp pair -> one b32 hi, one b32 lo
      unsigned int* arow32 = (unsigned int*)((char*)SA + q * 272);
      unsigned int hi2 = cvtpk(a, a2);
      arow32[kpl] = hi2;
      float rA = a  - bflo(hi2);
      float rB = a2 - bfhi(hi2);
      arow32[32 + kpl] = cvtpk(rA, rB);
    }
  }

  __syncthreads();   // all 4 waves reach unconditionally; per-wave data private

  // --- PV via MFMA (hi/lo compensated A), rinv epilogue ---
  {
    f32x4 o[2][2];
    #pragma unroll
    for (int i = 0; i < 2; ++i)
      #pragma unroll
      for (int j = 0; j < 2; ++j) o[i][j] = {0.f, 0.f, 0.f, 0.f};
    #pragma unroll
    for (int kx = 0; kx < 2; ++kx) {
      const int koff = kx * 64 + kgrp * 16;         // byte offset within hi block
      const char* sa = (const char*)SA;
      bf16x8 ah0 = *(const bf16x8*)(sa + cc * 272 + koff);
      bf16x8 ah1 = *(const bf16x8*)(sa + (cc + 16) * 272 + koff);
      bf16x8 al0 = *(const bf16x8*)(sa + cc * 272 + 128 + koff);
      bf16x8 al1 = *(const bf16x8*)(sa + (cc + 16) * 272 + 128 + koff);
      bf16x8 b0  = *(const bf16x8*)&vsT[cc * 72 + kx * 32 + ks8];
      bf16x8 b1  = *(const bf16x8*)&vsT[(cc + 16) * 72 + kx * 32 + ks8];
      o[0][0] = __builtin_amdgcn_mfma_f32_16x16x32_bf16(ah0, b0, o[0][0], 0, 0, 0);
      o[0][0] = __builtin_amdgcn_mfma_f32_16x16x32_bf16(al0, b0, o[0][0], 0, 0, 0);
      o[0][1] = __builtin_amdgcn_mfma_f32_16x16x32_bf16(ah0, b1, o[0][1], 0, 0, 0);
      o[0][1] = __builtin_amdgcn_mfma_f32_16x16x32_bf16(al0, b1, o[0][1], 0, 0, 0);
      o[1][0] = __builtin_amdgcn_mfma_f32_16x16x32_bf16(ah1, b0, o[1][0], 0, 0, 0);
      o[1][0] = __builtin_amdgcn_mfma_f32_16x16x32_bf16(al1, b0, o[1][0], 0, 0, 0);
      o[1][1] = __builtin_amdgcn_mfma_f32_16x16x32_bf16(ah1, b1, o[1][1], 0, 0, 0);
      o[1][1] = __builtin_amdgcn_mfma_f32_16x16x32_bf16(al1, b1, o[1][1], 0, 0, 0);
    }
    #pragma unroll
    for (int mt = 0; mt < 2; ++mt) {
      float4 rv = *(const float4*)&drow[mt * 16 + r0];
      #pragma unroll
      for (int i = 0; i < 4; ++i) {
        int q = mt * 16 + r0 + i;
        if (q < 25) {
          int qy = (q * 13) >> 6, qx = q - qy * 5;
          u16* dst = AO + gbase + ((size_t)((y0 + qy) * IMGW + x0 + qx)) * 32;
          float r = (&rv.x)[i];
          unsigned int pk = cvtpk(o[mt][0][i] * r, o[mt][1][i] * r);
          dst[cc]      = (u16)(pk & 0xffff);
          dst[cc + 16] = (u16)(pk >> 16);
        }
      }
    }
  }
}

// ---------------- K3: output projection via MFMA — LDS-free, barrier-free ----------------
__global__ __launch_bounds__(256) void outmm_kernel(
    const u16* __restrict__ AOb, const u16* __restrict__ Wb,
    const float* __restrict__ bout, float* __restrict__ O)
{
  const int t = threadIdx.x;
  const int lane = t & 63, wv = t >> 6;
  const int cc = lane & 15, kgrp = lane >> 4;
  const int p0 = blockIdx.x * 64;
  const int b  = blockIdx.y;
  const u16* Wm = Wb + (size_t)3 * 65536;

  f32x4 acc[4][4];
  #pragma unroll
  for (int i = 0; i < 4; ++i)
    #pragma unroll
    for (int j = 0; j < 4; ++j) acc[i][j] = {0.f, 0.f, 0.f, 0.f};

  for (int kk = 0; kk < 8; ++kk) {
    bf16x8 af[4], bfr[4];
    #pragma unroll
    for (int f = 0; f < 4; ++f)
      af[f] = *(const bf16x8*)(Wm + (size_t)(wv * 64 + f * 16 + cc) * 256 + kk * 32 + kgrp * 8);
    #pragma unroll
    for (int nt = 0; nt < 4; ++nt)
      bfr[nt] = *(const bf16x8*)(AOb + ((size_t)(b * 8 + kk) * NPIX + p0 + nt * 16 + cc) * 32 + kgrp * 8);
    #pragma unroll
    for (int df = 0; df < 4; ++df)
      #pragma unroll
      for (int pf = 0; pf < 4; ++pf)
        acc[df][pf] = __builtin_amdgcn_mfma_f32_16x16x32_bf16(af[df], bfr[pf], acc[df][pf], 0, 0, 0);
  }

  #pragma unroll
  for (int df = 0; df < 4; ++df) {
    int dim0 = wv * 64 + df * 16 + kgrp * 4;
    float4 bv = *(const float4*)&bout[dim0];
    #pragma unroll
    for (int pf = 0; pf < 4; ++pf) {
      int pix = p0 + pf * 16 + cc;
      f32x4 v = acc[df][pf];
      float* ob = O + (size_t)b * 256 * NPIX + pix;
      ob[(size_t)(dim0 + 0) * NPIX] = v[0] + bv.x;
      ob[(size_t)(dim0 + 1) * NPIX] = v[1] + bv.y;
      ob[(size_t)(dim0 + 2) * NPIX] = v[2] + bv.z;
      ob[(size_t)(dim0 + 3) * NPIX] = v[3] + bv.w;
    }
  }
}

extern "C" void kernel_launch(void* const* d_in, const int* in_sizes, int n_in,
                              void* d_out, int out_size, void* d_ws, size_t ws_size,
                              hipStream_t stream) {
  const float* x    = (const float*)d_in[0];
  const float* Wk   = (const float*)d_in[2];
  const float* Wv   = (const float*)d_in[3];
  const float* Wq   = (const float*)d_in[4];
  const float* Wout = (const float*)d_in[5];
  const float* bout = (const float*)d_in[6];

  // d_out: Qb bf16 (29,491,200 B) at base; overwritten by outmm's f32 output later
  u16* Qb  = (u16*)d_out;
  // ws: Kb | Vb | AOb (bf16) | Wb
  u16* Kb  = (u16*)d_ws;
  u16* Vb  = Kb + (size_t)4 * NPIX * 256;
  u16* AOb = Vb + (size_t)4 * NPIX * 256;
  u16* Wb  = AOb + (size_t)4 * NPIX * 256;

  wconv_kernel<<<dim3(64, 4), 256, 0, stream>>>(Wq, Wk, Wv, Wout, Wb);
  projmm_kernel<<<dim3(225, 4), 256, 0, stream>>>(x, Wb, Qb, Kb, Vb);
  attn_kernel<<<dim3(4608), 256, 0, stream>>>(Qb, Kb, Vb, AOb);
  outmm_kernel<<<dim3(225, 4), 256, 0, stream>>>(AOb, Wb, bout, (float*)d_out);
}